// Round 11
// baseline (307.282 us; speedup 1.0000x reference)
//
#include <hip/hip_runtime.h>
#include <hip/hip_bf16.h>
#include <hip/hip_fp16.h>
#include <math.h>

#define NL 4
#define Dm 512
#define FFD 1024
#define Bb 8
#define Ss 480
#define TPT 15
#define ROWS (Bb*Ss)   // 3840

typedef __attribute__((ext_vector_type(8))) short short8v;
typedef __attribute__((ext_vector_type(4))) float f32x4;
typedef __attribute__((ext_vector_type(2))) _Float16 half2v;
typedef __attribute__((ext_vector_type(8))) _Float16 half8v;

#if __has_builtin(__builtin_amdgcn_fdot2)
#define FDOT2(a, b, c) __builtin_amdgcn_fdot2(a, b, c, false)
#else
#define FDOT2(a, b, c) ((c) + (float)(a)[0] * (float)(b)[0] + (float)(a)[1] * (float)(b)[1])
#endif

// global -> LDS direct (16B/lane). lbase wave-uniform; HW dest = lbase + lane*16.
__device__ __forceinline__ void gld_lds16(const void* g, void* lbase) {
#if __has_builtin(__builtin_amdgcn_global_load_lds)
    __builtin_amdgcn_global_load_lds((const __attribute__((address_space(1))) void*)g,
                                     (__attribute__((address_space(3))) void*)lbase, 16, 0, 0);
#else
    (void)g; (void)lbase;
#endif
}

// ---------------- LayerNorm: one WAVE per row, D=512; bf16 out ------------------
__global__ __launch_bounds__(256) void ln_kernel(const float* __restrict__ x,
                                                 const float* __restrict__ g,
                                                 const float* __restrict__ b,
                                                 __hip_bfloat16* __restrict__ out) {
    int w = threadIdx.x >> 6, lane = threadIdx.x & 63;
    int row = blockIdx.x * 4 + w;
    const float* xr = x + (size_t)row * Dm + lane * 8;
    float4 v0 = *(const float4*)xr;
    float4 v1 = *(const float4*)(xr + 4);
    float v[8] = { v0.x, v0.y, v0.z, v0.w, v1.x, v1.y, v1.z, v1.w };

    float s = 0.0f;
#pragma unroll
    for (int e = 0; e < 8; e++) s += v[e];
#pragma unroll
    for (int off = 1; off < 64; off <<= 1) s += __shfl_xor(s, off);
    float mean = s * (1.0f / Dm);

    float ss = 0.0f;
#pragma unroll
    for (int e = 0; e < 8; e++) { v[e] -= mean; ss += v[e] * v[e]; }
#pragma unroll
    for (int off = 1; off < 64; off <<= 1) ss += __shfl_xor(ss, off);
    float rstd = rsqrtf(ss * (1.0f / Dm) + 1e-5f);

    const float* gp = g + lane * 8;
    const float* bp = b + lane * 8;
    float4 g0 = *(const float4*)gp, g1 = *(const float4*)(gp + 4);
    float4 b0 = *(const float4*)bp, b1 = *(const float4*)(bp + 4);
    float gg[8] = { g0.x, g0.y, g0.z, g0.w, g1.x, g1.y, g1.z, g1.w };
    float bb[8] = { b0.x, b0.y, b0.z, b0.w, b1.x, b1.y, b1.z, b1.w };
    short8v pack;
#pragma unroll
    for (int e = 0; e < 8; e++) {
        __hip_bfloat16 t = __float2bfloat16(v[e] * rstd * gg[e] + bb[e]);
        pack[e] = __builtin_bit_cast(short, t);
    }
    *(short8v*)&out[(size_t)row * Dm + lane * 8] = pack;
}

// -------- weight transpose+convert, exact tile list (no idle blocks) ------------
// [K][N] fp32 -> [N][K] bf16.  2048 tiles/layer x 4 layers = 8192 blocks.
__global__ __launch_bounds__(256) void conv_all(const float* __restrict__ Wqkv,
                                                const float* __restrict__ Wo,
                                                const float* __restrict__ W1,
                                                const float* __restrict__ W2,
                                                __hip_bfloat16* __restrict__ oq,
                                                __hip_bfloat16* __restrict__ oo,
                                                __hip_bfloat16* __restrict__ o1,
                                                __hip_bfloat16* __restrict__ o2) {
    int bid = blockIdx.x;
    int l = bid >> 11;              // / 2048
    int r = bid & 2047;
    int loc, K, N; const float* src; __hip_bfloat16* dst;
    if (r < 768)       { loc = r;        K = 512;  N = 1536; src = Wqkv; dst = oq; }
    else if (r < 1024) { loc = r - 768;  K = 512;  N = 512;  src = Wo;   dst = oo; }
    else if (r < 1536) { loc = r - 1024; K = 512;  N = 1024; src = W1;   dst = o1; }
    else               { loc = r - 1536; K = 1024; N = 512;  src = W2;   dst = o2; }
    int nx = N >> 5;
    int n0 = (loc % nx) * 32, k0 = (loc / nx) * 32;
    src += (size_t)l * K * N;
    dst += (size_t)l * K * N;

    __shared__ float t[32][33];
    int tx = threadIdx.x & 31, ty = threadIdx.x >> 5;
#pragma unroll
    for (int rr = 0; rr < 4; rr++)
        t[ty * 4 + rr][tx] = src[(size_t)(k0 + ty * 4 + rr) * N + n0 + tx];
    __syncthreads();
#pragma unroll
    for (int rr = 0; rr < 4; rr++)
        dst[(size_t)(n0 + ty * 4 + rr) * K + k0 + tx] = __float2bfloat16(t[tx][ty * 4 + rr]);
}

// ---- bf16 MFMA GEMM: BMxBN tile, BK=64, 4 waves, dbuf, XCD-swizzled grid -------
// C = act(A[M,K] @ Bt[N,K]^T + bias) (+res).  OUTMODE: 0 f32, 1 bf16, 2 f16.
// Grid must satisfy (gx*gy) % 8 == 0 for the bijective XCD swizzle.
template <int BM, int BN, int ACT, int RES, int OUTMODE>
__global__ __launch_bounds__(256) void gemm_mfma(const __hip_bfloat16* __restrict__ A,
                                                 const __hip_bfloat16* __restrict__ Bt,
                                                 const float* __restrict__ bias,
                                                 const float* __restrict__ res,
                                                 void* __restrict__ C,
                                                 int M, int N, int K) {
    constexpr int MF = BM / 32;          // m-frags per wave
    constexpr int NF = BN / 32;          // n-frags per wave
    constexpr int ACc = BM / 32;         // A staging chunk groups
    constexpr int BCc = BN / 32;         // B staging chunk groups
    __shared__ __align__(16) short As[2][BM * 64];
    __shared__ __align__(16) short Bs[2][BN * 64];

    // XCD-aware bijective swizzle (T1): contiguous chunk of tiles per XCD.
    int lin = blockIdx.y * gridDim.x + blockIdx.x;
    int nwg = gridDim.x * gridDim.y;
    int qq = nwg >> 3;                   // nwg % 8 == 0 by launch contract
    int swz = (lin & 7) * qq + (lin >> 3);
    int bx = swz % gridDim.x, by = swz / gridDim.x;

    const int bm = by * BM, bn = bx * BN;
    const int tid = threadIdx.x;
    const int w = tid >> 6, lane = tid & 63;
    const int wm = (w >> 1) * (BM / 2), wn = (w & 1) * (BN / 2);
    const int l16 = lane & 15, lq = lane >> 4;
    const short* Ag = (const short*)A;
    const short* Bg = (const short*)Bt;
    const int nt = K >> 6;

    f32x4 acc[MF][NF] = {};

    auto stage = [&](int t, int buf) {
        int k0 = t << 6;
#pragma unroll
        for (int c = 0; c < ACc; ++c) {
            int e = c * 256 + tid;                 // 16B chunk id
            int row = e >> 3;
            int csrc = (e & 7) ^ (row & 7);        // pre-swizzled source chunk
            gld_lds16(Ag + (size_t)(bm + row) * K + k0 + csrc * 8,
                      &As[buf][(c * 256 + w * 64) * 8]);
        }
#pragma unroll
        for (int c = 0; c < BCc; ++c) {
            int e = c * 256 + tid;
            int row = e >> 3;
            int csrc = (e & 7) ^ (row & 7);
            gld_lds16(Bg + (size_t)(bn + row) * K + k0 + csrc * 8,
                      &Bs[buf][(c * 256 + w * 64) * 8]);
        }
    };

    stage(0, 0);
    __syncthreads();                 // drains vmcnt(0) before first reads
    int cur = 0;
    for (int t = 0; t < nt; ++t) {
        if (t + 1 < nt) stage(t + 1, cur ^ 1);   // prefetch next tile
#pragma unroll
        for (int kc = 0; kc < 2; ++kc) {
            short8v af[MF], bf[NF];
#pragma unroll
            for (int i = 0; i < MF; i++) {
                int row = wm + i * 16 + l16;
                int ch = (kc * 4 + lq) ^ (row & 7);
                af[i] = *(const short8v*)(&As[cur][row * 64 + ch * 8]);
            }
#pragma unroll
            for (int j = 0; j < NF; j++) {
                int col = wn + j * 16 + l16;
                int ch2 = (kc * 4 + lq) ^ (col & 7);
                bf[j] = *(const short8v*)(&Bs[cur][col * 64 + ch2 * 8]);
            }
#pragma unroll
            for (int i = 0; i < MF; i++)
#pragma unroll
                for (int j = 0; j < NF; j++)
                    acc[i][j] = __builtin_amdgcn_mfma_f32_16x16x32_bf16(
                        af[i], bf[j], acc[i][j], 0, 0, 0);
        }
        __syncthreads();             // next tile ready, reads done
        cur ^= 1;
    }

#pragma unroll
    for (int i = 0; i < MF; i++) {
#pragma unroll
        for (int j = 0; j < NF; j++) {
#pragma unroll
            for (int r = 0; r < 4; r++) {
                int mrow = bm + wm + i * 16 + lq * 4 + r;
                int ncol = bn + wn + j * 16 + l16;
                float v = acc[i][j][r] + bias[ncol];
                if (ACT == 1) v = 0.5f * v * (1.0f + erff(v * 0.70710678118f));
                if (RES) v += res[(size_t)mrow * N + ncol];
                if (OUTMODE == 0)      ((float*)C)[(size_t)mrow * N + ncol] = v;
                else if (OUTMODE == 1) ((__hip_bfloat16*)C)[(size_t)mrow * N + ncol] = __float2bfloat16(v);
                else                   ((__half*)C)[(size_t)mrow * N + ncol] = __float2half(v);
            }
        }
    }
}

// ------------- Attention: 1 wave per (b,q), all 8 heads, f16 fdot2 --------------
// Barrier-free: qs is wave-private; p broadcast via intra-group __shfl.
// XCD-chunked block swizzle: contiguous bq range per XCD -> K/V window L2-fits.
__global__ __launch_bounds__(256) void attn_sparse(const _Float16* __restrict__ qkv,
                                                   const int* __restrict__ ids,
                                                   const int* __restrict__ npf_p,
                                                   __hip_bfloat16* __restrict__ outb) {
    __shared__ _Float16 qs[4][512];
    int w = threadIdx.x >> 6, lane = threadIdx.x & 63;
    int bid = blockIdx.x;                       // 960 blocks, %8==0
    int swb = (bid & 7) * 120 + (bid >> 3);     // bijective chunked swizzle
    int bq = swb * 4 + w;
    int q = bq % Ss, b = bq / Ss;
    int npf = npf_p[0];
    int qt = q / TPT;
    int qid = ids[bq];

    // stage q row (wave-private; no cross-wave barrier needed)
    *(half8v*)&qs[w][lane * 8] = *(const half8v*)&qkv[(size_t)bq * 1536 + lane * 8];

    int h = lane >> 3, cp = lane & 7;

    half2v qreg[32];
#pragma unroll
    for (int i = 0; i < 32; i++) qreg[i] = *(const half2v*)&qs[w][h * 64 + i * 2];

    float s[3];
#pragma unroll
    for (int i = 0; i < 3; i++) {
        int c = cp + i * 8;
        float sv = -INFINITY;
        if (c < 23) {
            bool ok; int k;
            if (c < 15) { k = qt * TPT + c; ok = true; }
            else { int dt = c - 14; int kt = qt - dt; k = kt * TPT; ok = (kt >= 0) && (dt <= npf); }
            if (ok && ids[b * Ss + k] == qid) {
                const half8v* kr = (const half8v*)&qkv[(size_t)(b * Ss + k) * 1536 + 512 + h * 64];
                float dot = 0.0f;
#pragma unroll
                for (int cch = 0; cch < 8; cch++) {
                    half8v kv = kr[cch];
#pragma unroll
                    for (int e = 0; e < 4; e++) {
                        half2v kk = { kv[e * 2], kv[e * 2 + 1] };
                        dot = FDOT2(qreg[cch * 4 + e], kk, dot);
                    }
                }
                // 6*tanh((dot/8)/6) via hardware exp
                float y = dot * (0.125f / 6.0f);
                float e2 = __expf(2.0f * y);
                sv = 6.0f * (e2 - 1.0f) / (e2 + 1.0f);
            }
        }
        s[i] = sv;
    }

    float m = fmaxf(fmaxf(s[0], s[1]), s[2]);
    for (int off = 1; off < 8; off <<= 1) m = fmaxf(m, __shfl_xor(m, off));
    float p0 = __expf(s[0] - m), p1 = __expf(s[1] - m), p2 = __expf(s[2] - m);
    float l = p0 + p1 + p2;
    for (int off = 1; off < 8; off <<= 1) l += __shfl_xor(l, off);
    float inv = 1.0f / l;
    float pn0 = p0 * inv, pn1 = p1 * inv, pn2 = p2 * inv;

    // PV: lane = (h, dg); p broadcast from owning lane of the same 8-lane group
    int dg = lane & 7;
    int gbase = lane & 56;
    float o[8] = {};
    for (int c = 0; c < 23; c++) {
        float psel = (c < 8) ? pn0 : (c < 16) ? pn1 : pn2;
        float pj = __shfl(psel, gbase + (c & 7));
        if (pj > 0.0f) {
            int k = (c < 15) ? (qt * TPT + c) : ((qt - (c - 14)) * TPT);
            half8v vv = *(const half8v*)&qkv[(size_t)(b * Ss + k) * 1536 + 1024 + h * 64 + dg * 8];
#pragma unroll
            for (int e = 0; e < 8; e++) o[e] += pj * (float)vv[e];
        }
    }
    short8v pack;
#pragma unroll
    for (int e = 0; e < 8; e++) {
        __hip_bfloat16 t = __float2bfloat16(o[e]);
        pack[e] = __builtin_bit_cast(short, t);
    }
    *(short8v*)&outb[(size_t)bq * Dm + h * 64 + dg * 8] = pack;
}

extern "C" void kernel_launch(void* const* d_in, const int* in_sizes, int n_in,
                              void* d_out, int out_size, void* d_ws, size_t ws_size,
                              hipStream_t stream) {
    const float* x    = (const float*)d_in[0];
    const int*   ids  = (const int*)d_in[1];
    const int*   npf  = (const int*)d_in[2];
    const float* Wqkv = (const float*)d_in[3];
    const float* bqkv = (const float*)d_in[4];
    const float* Wo   = (const float*)d_in[5];
    const float* bo   = (const float*)d_in[6];
    const float* g1   = (const float*)d_in[7];
    const float* b1   = (const float*)d_in[8];
    const float* g2   = (const float*)d_in[9];
    const float* b2   = (const float*)d_in[10];
    const float* W1   = (const float*)d_in[11];
    const float* bf1  = (const float*)d_in[12];
    const float* W2   = (const float*)d_in[13];
    const float* bf2  = (const float*)d_in[14];
    float* out = (float*)d_out;

    char* p = (char*)d_ws;
    __hip_bfloat16* hb    = (__hip_bfloat16*)p;   p += (size_t)ROWS * Dm * 2;
    _Float16*       qkvb  = (_Float16*)p;         p += (size_t)ROWS * 3 * Dm * 2;
    __hip_bfloat16* attnb = (__hip_bfloat16*)p;   p += (size_t)ROWS * Dm * 2;
    __hip_bfloat16* fb    = (__hip_bfloat16*)p;   p += (size_t)ROWS * FFD * 2;
    __hip_bfloat16* Wqkv_t= (__hip_bfloat16*)p;   p += (size_t)NL * Dm * 3 * Dm * 2;
    __hip_bfloat16* Wo_t  = (__hip_bfloat16*)p;   p += (size_t)NL * Dm * Dm * 2;
    __hip_bfloat16* W1_t  = (__hip_bfloat16*)p;   p += (size_t)NL * Dm * FFD * 2;
    __hip_bfloat16* W2_t  = (__hip_bfloat16*)p;   p += (size_t)NL * FFD * Dm * 2;

    conv_all<<<8192, 256, 0, stream>>>(Wqkv, Wo, W1, W2, Wqkv_t, Wo_t, W1_t, W2_t);

    for (int l = 0; l < NL; l++) {
        const float* xin = (l == 0) ? x : out;
        ln_kernel<<<ROWS / 4, 256, 0, stream>>>(xin, g1 + l * Dm, b1 + l * Dm, hb);
        // QKV: 64x64 dbuf -> f16   (1440 blocks, 5.6/CU)
        gemm_mfma<64, 64, 0, 0, 2><<<dim3(24, 60), 256, 0, stream>>>(
            hb, Wqkv_t + (size_t)l * Dm * 3 * Dm, bqkv + l * 3 * Dm, nullptr, qkvb,
            ROWS, 3 * Dm, Dm);
        attn_sparse<<<ROWS / 4, 256, 0, stream>>>(qkvb, ids, npf, attnb);
        // Wo + residual: 64x64 dbuf -> fp32   (480 blocks)
        gemm_mfma<64, 64, 0, 1, 0><<<dim3(8, 60), 256, 0, stream>>>(
            attnb, Wo_t + (size_t)l * Dm * Dm, bo + l * Dm, xin, out,
            ROWS, Dm, Dm);
        ln_kernel<<<ROWS / 4, 256, 0, stream>>>(out, g2 + l * Dm, b2 + l * Dm, hb);
        // FF1 + GELU: 64x64 dbuf -> bf16   (960 blocks)
        gemm_mfma<64, 64, 1, 0, 1><<<dim3(16, 60), 256, 0, stream>>>(
            hb, W1_t + (size_t)l * Dm * FFD, bf1 + l * FFD, nullptr, fb,
            ROWS, FFD, Dm);
        // FF2 + residual: 64x64 dbuf -> fp32 (in-place)   (480 blocks)
        gemm_mfma<64, 64, 0, 1, 0><<<dim3(8, 60), 256, 0, stream>>>(
            fb, W2_t + (size_t)l * FFD * Dm, bf2 + l * Dm, out, out,
            ROWS, Dm, FFD);
    }
}

// Round 12
// 302.742 us; speedup vs baseline: 1.0150x; 1.0150x over previous
//
#include <hip/hip_runtime.h>
#include <hip/hip_bf16.h>
#include <hip/hip_fp16.h>
#include <math.h>

#define NL 4
#define Dm 512
#define FFD 1024
#define Bb 8
#define Ss 480
#define TPT 15
#define ROWS (Bb*Ss)   // 3840

typedef __attribute__((ext_vector_type(8))) short short8v;
typedef __attribute__((ext_vector_type(4))) float f32x4;
typedef __attribute__((ext_vector_type(2))) _Float16 half2v;
typedef __attribute__((ext_vector_type(8))) _Float16 half8v;

#if __has_builtin(__builtin_amdgcn_fdot2)
#define FDOT2(a, b, c) __builtin_amdgcn_fdot2(a, b, c, false)
#else
#define FDOT2(a, b, c) ((c) + (float)(a)[0] * (float)(b)[0] + (float)(a)[1] * (float)(b)[1])
#endif

// global -> LDS direct (16B/lane). lbase wave-uniform; HW dest = lbase + lane*16.
__device__ __forceinline__ void gld_lds16(const void* g, void* lbase) {
#if __has_builtin(__builtin_amdgcn_global_load_lds)
    __builtin_amdgcn_global_load_lds((const __attribute__((address_space(1))) void*)g,
                                     (__attribute__((address_space(3))) void*)lbase, 16, 0, 0);
#else
    (void)g; (void)lbase;
#endif
}

// ---------------- LayerNorm: one WAVE per row, D=512; bf16 out ------------------
__global__ __launch_bounds__(256) void ln_kernel(const float* __restrict__ x,
                                                 const float* __restrict__ g,
                                                 const float* __restrict__ b,
                                                 __hip_bfloat16* __restrict__ out) {
    int w = threadIdx.x >> 6, lane = threadIdx.x & 63;
    int row = blockIdx.x * 4 + w;
    const float* xr = x + (size_t)row * Dm + lane * 8;
    float4 v0 = *(const float4*)xr;
    float4 v1 = *(const float4*)(xr + 4);
    float v[8] = { v0.x, v0.y, v0.z, v0.w, v1.x, v1.y, v1.z, v1.w };

    float s = 0.0f;
#pragma unroll
    for (int e = 0; e < 8; e++) s += v[e];
#pragma unroll
    for (int off = 1; off < 64; off <<= 1) s += __shfl_xor(s, off);
    float mean = s * (1.0f / Dm);

    float ss = 0.0f;
#pragma unroll
    for (int e = 0; e < 8; e++) { v[e] -= mean; ss += v[e] * v[e]; }
#pragma unroll
    for (int off = 1; off < 64; off <<= 1) ss += __shfl_xor(ss, off);
    float rstd = rsqrtf(ss * (1.0f / Dm) + 1e-5f);

    const float* gp = g + lane * 8;
    const float* bp = b + lane * 8;
    float4 g0 = *(const float4*)gp, g1 = *(const float4*)(gp + 4);
    float4 b0 = *(const float4*)bp, b1 = *(const float4*)(bp + 4);
    float gg[8] = { g0.x, g0.y, g0.z, g0.w, g1.x, g1.y, g1.z, g1.w };
    float bb[8] = { b0.x, b0.y, b0.z, b0.w, b1.x, b1.y, b1.z, b1.w };
    short8v pack;
#pragma unroll
    for (int e = 0; e < 8; e++) {
        __hip_bfloat16 t = __float2bfloat16(v[e] * rstd * gg[e] + bb[e]);
        pack[e] = __builtin_bit_cast(short, t);
    }
    *(short8v*)&out[(size_t)row * Dm + lane * 8] = pack;
}

// -------- weight transpose+convert, exact tile list (no idle blocks) ------------
// [K][N] fp32 -> [N][K] bf16.  2048 tiles/layer x 4 layers = 8192 blocks.
__global__ __launch_bounds__(256) void conv_all(const float* __restrict__ Wqkv,
                                                const float* __restrict__ Wo,
                                                const float* __restrict__ W1,
                                                const float* __restrict__ W2,
                                                __hip_bfloat16* __restrict__ oq,
                                                __hip_bfloat16* __restrict__ oo,
                                                __hip_bfloat16* __restrict__ o1,
                                                __hip_bfloat16* __restrict__ o2) {
    int bid = blockIdx.x;
    int l = bid >> 11;              // / 2048
    int r = bid & 2047;
    int loc, K, N; const float* src; __hip_bfloat16* dst;
    if (r < 768)       { loc = r;        K = 512;  N = 1536; src = Wqkv; dst = oq; }
    else if (r < 1024) { loc = r - 768;  K = 512;  N = 512;  src = Wo;   dst = oo; }
    else if (r < 1536) { loc = r - 1024; K = 512;  N = 1024; src = W1;   dst = o1; }
    else               { loc = r - 1536; K = 1024; N = 512;  src = W2;   dst = o2; }
    int nx = N >> 5;
    int n0 = (loc % nx) * 32, k0 = (loc / nx) * 32;
    src += (size_t)l * K * N;
    dst += (size_t)l * K * N;

    __shared__ float t[32][33];
    int tx = threadIdx.x & 31, ty = threadIdx.x >> 5;
#pragma unroll
    for (int rr = 0; rr < 4; rr++)
        t[ty * 4 + rr][tx] = src[(size_t)(k0 + ty * 4 + rr) * N + n0 + tx];
    __syncthreads();
#pragma unroll
    for (int rr = 0; rr < 4; rr++)
        dst[(size_t)(n0 + ty * 4 + rr) * K + k0 + tx] = __float2bfloat16(t[tx][ty * 4 + rr]);
}

// ---- bf16 MFMA GEMM: BMxBN tile, BK=64, 4 waves, dbuf, XCD-swizzled grid -------
// C = act(A[M,K] @ Bt[N,K]^T + bias) (+res).  OUTMODE: 0 f32, 1 bf16, 2 f16.
// Grid must satisfy (gx*gy) % 8 == 0 for the bijective XCD swizzle.
template <int BM, int BN, int ACT, int RES, int OUTMODE>
__global__ __launch_bounds__(256) void gemm_mfma(const __hip_bfloat16* __restrict__ A,
                                                 const __hip_bfloat16* __restrict__ Bt,
                                                 const float* __restrict__ bias,
                                                 const float* __restrict__ res,
                                                 void* __restrict__ C,
                                                 int M, int N, int K) {
    constexpr int MF = BM / 32;          // m-frags per wave
    constexpr int NF = BN / 32;          // n-frags per wave
    constexpr int ACc = BM / 32;         // A staging chunk groups
    constexpr int BCc = BN / 32;         // B staging chunk groups
    __shared__ __align__(16) short As[2][BM * 64];
    __shared__ __align__(16) short Bs[2][BN * 64];

    // XCD-aware bijective swizzle (T1): contiguous chunk of tiles per XCD.
    int lin = blockIdx.y * gridDim.x + blockIdx.x;
    int nwg = gridDim.x * gridDim.y;
    int qq = nwg >> 3;                   // nwg % 8 == 0 by launch contract
    int swz = (lin & 7) * qq + (lin >> 3);
    int bx = swz % gridDim.x, by = swz / gridDim.x;

    const int bm = by * BM, bn = bx * BN;
    const int tid = threadIdx.x;
    const int w = tid >> 6, lane = tid & 63;
    const int wm = (w >> 1) * (BM / 2), wn = (w & 1) * (BN / 2);
    const int l16 = lane & 15, lq = lane >> 4;
    const short* Ag = (const short*)A;
    const short* Bg = (const short*)Bt;
    const int nt = K >> 6;

    f32x4 acc[MF][NF] = {};

    auto stage = [&](int t, int buf) {
        int k0 = t << 6;
#pragma unroll
        for (int c = 0; c < ACc; ++c) {
            int e = c * 256 + tid;                 // 16B chunk id
            int row = e >> 3;
            int csrc = (e & 7) ^ (row & 7);        // pre-swizzled source chunk
            gld_lds16(Ag + (size_t)(bm + row) * K + k0 + csrc * 8,
                      &As[buf][(c * 256 + w * 64) * 8]);
        }
#pragma unroll
        for (int c = 0; c < BCc; ++c) {
            int e = c * 256 + tid;
            int row = e >> 3;
            int csrc = (e & 7) ^ (row & 7);
            gld_lds16(Bg + (size_t)(bn + row) * K + k0 + csrc * 8,
                      &Bs[buf][(c * 256 + w * 64) * 8]);
        }
    };

    stage(0, 0);
    __syncthreads();                 // drains vmcnt(0) before first reads
    int cur = 0;
    for (int t = 0; t < nt; ++t) {
        if (t + 1 < nt) stage(t + 1, cur ^ 1);   // prefetch next tile
#pragma unroll
        for (int kc = 0; kc < 2; ++kc) {
            short8v af[MF], bf[NF];
#pragma unroll
            for (int i = 0; i < MF; i++) {
                int row = wm + i * 16 + l16;
                int ch = (kc * 4 + lq) ^ (row & 7);
                af[i] = *(const short8v*)(&As[cur][row * 64 + ch * 8]);
            }
#pragma unroll
            for (int j = 0; j < NF; j++) {
                int col = wn + j * 16 + l16;
                int ch2 = (kc * 4 + lq) ^ (col & 7);
                bf[j] = *(const short8v*)(&Bs[cur][col * 64 + ch2 * 8]);
            }
#pragma unroll
            for (int i = 0; i < MF; i++)
#pragma unroll
                for (int j = 0; j < NF; j++)
                    acc[i][j] = __builtin_amdgcn_mfma_f32_16x16x32_bf16(
                        af[i], bf[j], acc[i][j], 0, 0, 0);
        }
        __syncthreads();             // next tile ready, reads done
        cur ^= 1;
    }

#pragma unroll
    for (int i = 0; i < MF; i++) {
#pragma unroll
        for (int j = 0; j < NF; j++) {
#pragma unroll
            for (int r = 0; r < 4; r++) {
                int mrow = bm + wm + i * 16 + lq * 4 + r;
                int ncol = bn + wn + j * 16 + l16;
                float v = acc[i][j][r] + bias[ncol];
                if (ACT == 1) v = 0.5f * v * (1.0f + erff(v * 0.70710678118f));
                if (RES) v += res[(size_t)mrow * N + ncol];
                if (OUTMODE == 0)      ((float*)C)[(size_t)mrow * N + ncol] = v;
                else if (OUTMODE == 1) ((__hip_bfloat16*)C)[(size_t)mrow * N + ncol] = __float2bfloat16(v);
                else                   ((__half*)C)[(size_t)mrow * N + ncol] = __float2half(v);
            }
        }
    }
}

// ------------- Attention: 1 wave per (b,q), all 8 heads, f16 fdot2 --------------
// Barrier-free: qs is wave-private; p broadcast via intra-group __shfl.
// XCD-chunked block swizzle: contiguous bq range per XCD -> K/V window L2-fits.
__global__ __launch_bounds__(256) void attn_sparse(const _Float16* __restrict__ qkv,
                                                   const int* __restrict__ ids,
                                                   const int* __restrict__ npf_p,
                                                   __hip_bfloat16* __restrict__ outb) {
    __shared__ _Float16 qs[4][512];
    int w = threadIdx.x >> 6, lane = threadIdx.x & 63;
    int bid = blockIdx.x;                       // 960 blocks, %8==0
    int swb = (bid & 7) * 120 + (bid >> 3);     // bijective chunked swizzle
    int bq = swb * 4 + w;
    int q = bq % Ss, b = bq / Ss;
    int npf = npf_p[0];
    int qt = q / TPT;
    int qid = ids[bq];

    // stage q row (wave-private; no cross-wave barrier needed)
    *(half8v*)&qs[w][lane * 8] = *(const half8v*)&qkv[(size_t)bq * 1536 + lane * 8];

    int h = lane >> 3, cp = lane & 7;

    half2v qreg[32];
#pragma unroll
    for (int i = 0; i < 32; i++) qreg[i] = *(const half2v*)&qs[w][h * 64 + i * 2];

    float s[3];
#pragma unroll
    for (int i = 0; i < 3; i++) {
        int c = cp + i * 8;
        float sv = -INFINITY;
        if (c < 23) {
            bool ok; int k;
            if (c < 15) { k = qt * TPT + c; ok = true; }
            else { int dt = c - 14; int kt = qt - dt; k = kt * TPT; ok = (kt >= 0) && (dt <= npf); }
            if (ok && ids[b * Ss + k] == qid) {
                const half8v* kr = (const half8v*)&qkv[(size_t)(b * Ss + k) * 1536 + 512 + h * 64];
                float dot = 0.0f;
#pragma unroll
                for (int cch = 0; cch < 8; cch++) {
                    half8v kv = kr[cch];
#pragma unroll
                    for (int e = 0; e < 4; e++) {
                        half2v kk = { kv[e * 2], kv[e * 2 + 1] };
                        dot = FDOT2(qreg[cch * 4 + e], kk, dot);
                    }
                }
                // 6*tanh((dot/8)/6) via hardware exp
                float y = dot * (0.125f / 6.0f);
                float e2 = __expf(2.0f * y);
                sv = 6.0f * (e2 - 1.0f) / (e2 + 1.0f);
            }
        }
        s[i] = sv;
    }

    float m = fmaxf(fmaxf(s[0], s[1]), s[2]);
    for (int off = 1; off < 8; off <<= 1) m = fmaxf(m, __shfl_xor(m, off));
    float p0 = __expf(s[0] - m), p1 = __expf(s[1] - m), p2 = __expf(s[2] - m);
    float l = p0 + p1 + p2;
    for (int off = 1; off < 8; off <<= 1) l += __shfl_xor(l, off);
    float inv = 1.0f / l;
    float pn0 = p0 * inv, pn1 = p1 * inv, pn2 = p2 * inv;

    // PV: lane = (h, dg); p broadcast from owning lane of the same 8-lane group
    int dg = lane & 7;
    int gbase = lane & 56;
    float o[8] = {};
    for (int c = 0; c < 23; c++) {
        float psel = (c < 8) ? pn0 : (c < 16) ? pn1 : pn2;
        float pj = __shfl(psel, gbase + (c & 7));
        if (pj > 0.0f) {
            int k = (c < 15) ? (qt * TPT + c) : ((qt - (c - 14)) * TPT);
            half8v vv = *(const half8v*)&qkv[(size_t)(b * Ss + k) * 1536 + 1024 + h * 64 + dg * 8];
#pragma unroll
            for (int e = 0; e < 8; e++) o[e] += pj * (float)vv[e];
        }
    }
    short8v pack;
#pragma unroll
    for (int e = 0; e < 8; e++) {
        __hip_bfloat16 t = __float2bfloat16(o[e]);
        pack[e] = __builtin_bit_cast(short, t);
    }
    *(short8v*)&outb[(size_t)bq * Dm + h * 64 + dg * 8] = pack;
}

extern "C" void kernel_launch(void* const* d_in, const int* in_sizes, int n_in,
                              void* d_out, int out_size, void* d_ws, size_t ws_size,
                              hipStream_t stream) {
    const float* x    = (const float*)d_in[0];
    const int*   ids  = (const int*)d_in[1];
    const int*   npf  = (const int*)d_in[2];
    const float* Wqkv = (const float*)d_in[3];
    const float* bqkv = (const float*)d_in[4];
    const float* Wo   = (const float*)d_in[5];
    const float* bo   = (const float*)d_in[6];
    const float* g1   = (const float*)d_in[7];
    const float* b1   = (const float*)d_in[8];
    const float* g2   = (const float*)d_in[9];
    const float* b2   = (const float*)d_in[10];
    const float* W1   = (const float*)d_in[11];
    const float* bf1  = (const float*)d_in[12];
    const float* W2   = (const float*)d_in[13];
    const float* bf2  = (const float*)d_in[14];
    float* out = (float*)d_out;

    char* p = (char*)d_ws;
    __hip_bfloat16* hb    = (__hip_bfloat16*)p;   p += (size_t)ROWS * Dm * 2;
    _Float16*       qkvb  = (_Float16*)p;         p += (size_t)ROWS * 3 * Dm * 2;
    __hip_bfloat16* attnb = (__hip_bfloat16*)p;   p += (size_t)ROWS * Dm * 2;
    __hip_bfloat16* fb    = (__hip_bfloat16*)p;   p += (size_t)ROWS * FFD * 2;
    __hip_bfloat16* Wqkv_t= (__hip_bfloat16*)p;   p += (size_t)NL * Dm * 3 * Dm * 2;
    __hip_bfloat16* Wo_t  = (__hip_bfloat16*)p;   p += (size_t)NL * Dm * Dm * 2;
    __hip_bfloat16* W1_t  = (__hip_bfloat16*)p;   p += (size_t)NL * Dm * FFD * 2;
    __hip_bfloat16* W2_t  = (__hip_bfloat16*)p;   p += (size_t)NL * FFD * Dm * 2;

    conv_all<<<8192, 256, 0, stream>>>(Wqkv, Wo, W1, W2, Wqkv_t, Wo_t, W1_t, W2_t);

    for (int l = 0; l < NL; l++) {
        const float* xin = (l == 0) ? x : out;
        ln_kernel<<<ROWS / 4, 256, 0, stream>>>(xin, g1 + l * Dm, b1 + l * Dm, hb);
        // QKV: 128x64 dbuf -> f16   (720 blocks, %8==0)
        gemm_mfma<128, 64, 0, 0, 2><<<dim3(24, 30), 256, 0, stream>>>(
            hb, Wqkv_t + (size_t)l * Dm * 3 * Dm, bqkv + l * 3 * Dm, nullptr, qkvb,
            ROWS, 3 * Dm, Dm);
        attn_sparse<<<ROWS / 4, 256, 0, stream>>>(qkvb, ids, npf, attnb);
        // Wo + residual: 64x64 dbuf -> fp32   (480 blocks, 2+ blocks/CU)
        gemm_mfma<64, 64, 0, 1, 0><<<dim3(8, 60), 256, 0, stream>>>(
            attnb, Wo_t + (size_t)l * Dm * Dm, bo + l * Dm, xin, out,
            ROWS, Dm, Dm);
        ln_kernel<<<ROWS / 4, 256, 0, stream>>>(out, g2 + l * Dm, b2 + l * Dm, hb);
        // FF1 + GELU: 128x64 dbuf -> bf16   (480 blocks)
        gemm_mfma<128, 64, 1, 0, 1><<<dim3(16, 30), 256, 0, stream>>>(
            hb, W1_t + (size_t)l * Dm * FFD, bf1 + l * FFD, nullptr, fb,
            ROWS, FFD, Dm);
        // FF2 + residual: 64x64 dbuf -> fp32 (in-place)   (480 blocks)
        gemm_mfma<64, 64, 0, 1, 0><<<dim3(8, 60), 256, 0, stream>>>(
            fb, W2_t + (size_t)l * FFD * Dm, bf2 + l * Dm, out, out,
            ROWS, Dm, FFD);
    }
}